// Round 3
// baseline (34.218 us; speedup 1.0000x reference)
//
#include <hip/hip_runtime.h>

// Fully-fused 4-level db4 wavedec ('symmetric'), register-sliding-window version.
// x: [B=64, L=4096, C=32] f32.  Out flat concat: cA4,cD4,cD3,cD2,cD1 each [B,C,len].
// lens: 4096 -> 2051 -> 1029 -> 518 -> 262.
// Block = (batch, channel-group of 8, tile of 33 cA4 outputs). LDS rows are
// transposed [ch][sample] with 6-left/7-right reflection margins; compute
// threads own runs of R consecutive outputs and read one ds_read_b64 per output.

#define NCH 8
// Row pitches (words): 6 + max_span + 7, rounded so pitch ≡ 2 (mod 4) => pitch/2 odd
// (makes (c,slot)->bank map uniform => conflict-free b64 reads).
#define LPX 634  // x span <= 618
#define LP1 322  // l1 span <= 306
#define LP2 166  // l2 span <= 150
#define LP3 86   // l3 span <= 72

template <int R, bool LAST>
__device__ __forceinline__ void level_run(
    const float* __restrict__ src, int LPS, int srclo,
    float* __restrict__ dst, int LPD, int DL,
    int lo, int hi,
    float* __restrict__ gcd, int ownLo, int ownHi,
    float* __restrict__ gca, int c, int slot) {
    // db4 correlation kernels (dec_lo reversed = _H; dec_hi reversed).
    constexpr float FLO[8] = {
        0.23037781330885523f,  0.7148465705525415f,  0.6308807679295904f,
        -0.02798376941698385f, -0.18703481171888114f, 0.030841381835986965f,
        0.032883011666982945f, -0.010597401784997278f};
    constexpr float FHI[8] = {
        -0.010597401784997278f, -0.032883011666982945f, 0.030841381835986965f,
        0.18703481171888114f,  -0.02798376941698385f,  -0.6308807679295904f,
        0.7148465705525415f,   -0.23037781330885523f};

    const int span = hi - lo;
    int i0r = slot * R;
    if (i0r > span - R) i0r = span - R;  // span >= R guaranteed by tiling
    const int i0 = lo + i0r;

    const float2* row2 = reinterpret_cast<const float2*>(src + c * LPS);
    int p = i0 - (srclo >> 1);  // sample t stored at word t - srclo + 6; first tap = 2i-6
    float2 f0 = row2[p], f1 = row2[p + 1], f2 = row2[p + 2];
    float* drow = LAST ? nullptr : dst + c * LPD;

#pragma unroll
    for (int r = 0; r < R; ++r) {
        const float2 f3 = row2[p + 3 + r];
        const int i = i0 + r;
        const float w0 = f0.x, w1 = f0.y, w2 = f1.x, w3 = f1.y;
        const float w4 = f2.x, w5 = f2.y, w6 = f3.x, w7 = f3.y;
        float a = FLO[0] * w0;
        a = fmaf(FLO[1], w1, a); a = fmaf(FLO[2], w2, a); a = fmaf(FLO[3], w3, a);
        a = fmaf(FLO[4], w4, a); a = fmaf(FLO[5], w5, a); a = fmaf(FLO[6], w6, a);
        a = fmaf(FLO[7], w7, a);
        float d = FHI[0] * w0;
        d = fmaf(FHI[1], w1, d); d = fmaf(FHI[2], w2, d); d = fmaf(FHI[3], w3, d);
        d = fmaf(FHI[4], w4, d); d = fmaf(FHI[5], w5, d); d = fmaf(FHI[6], w6, d);
        d = fmaf(FHI[7], w7, d);

        if constexpr (!LAST) {
            drow[i - lo + 6] = a;
            // reflection margins for the next level (boundary tiles only)
            if (lo == 0 && i < 6) drow[5 - i] = a;
            if (hi == DL && i >= DL - 7) drow[(2 * DL - 1 - i) - lo + 6] = a;
        } else {
            gca[i] = a;
        }
        if (i >= ownLo && i < ownHi) gcd[i] = d;
        f0 = f1; f1 = f2; f2 = f3;
    }
}

__global__ __launch_bounds__(256) void fused_dwt_kernel(
    const float* __restrict__ x, float* __restrict__ out) {
    __shared__ __align__(16) float bx[NCH * LPX];
    __shared__ __align__(16) float b1[NCH * LP1];
    __shared__ __align__(16) float b2[NCH * LP2];
    __shared__ __align__(16) float b3[NCH * LP3];

    // XCD swizzle: 2048 blocks = 8 XCDs x 256; contiguous chunk per XCD so the
    // 4 channel-group siblings (consecutive work ids) share one L2.
    const int bid = blockIdx.x;
    const int work = (bid & 7) * 256 + (bid >> 3);
    const int cg = work & 3;           // channel group 0..3
    const int tile = (work >> 2) & 7;  // cA4 tile 0..7
    const int b = work >> 5;           // batch 0..63

    const int tid = threadIdx.x;
    const int c = tid & 7;
    const int slot = tid >> 3;  // 0..31
    const int c0 = cg * 8;

    const int L0 = 4096, L1 = 2051, L2 = 1029, L3 = 518, L4 = 262;

    const int lo4 = tile * 33, hi4 = min(L4, lo4 + 33);
    const int lo3 = max(0, 2 * lo4 - 6), hi3 = min(L3, 2 * hi4);
    const int lo2 = max(0, 2 * lo3 - 6), hi2 = min(L2, 2 * hi3);
    const int lo1 = max(0, 2 * lo2 - 6), hi1 = min(L1, 2 * hi2);
    const int lox = max(0, 2 * lo1 - 6), hix = min(L0, 2 * hi1);

    // ---- stage x tile into transposed rows (+ reflection margins) ----
    const float* xb = x + (size_t)b * L0 * 32 + c0;
    const int nx = hix - lox;
    for (int q = tid; q < nx * 2; q += 256) {
        const int jj = q >> 1;
        const int h = (q & 1) * 4;
        const int t = lox + jj;
        const float4 v = *reinterpret_cast<const float4*>(xb + (size_t)t * 32 + h);
        const float vv[4] = {v.x, v.y, v.z, v.w};
#pragma unroll
        for (int hh = 0; hh < 4; ++hh) {
            float* row = bx + (h + hh) * LPX;
            row[jj + 6] = vv[hh];
            if (lox == 0 && t < 6) row[5 - t] = vv[hh];
            if (hix == L0 && t >= L0 - 7) row[(2 * L0 - 1 - t) - lox + 6] = vv[hh];
        }
    }
    __syncthreads();

    // d_out chunk pointers for this signal
    const size_t S = 2048;
    const size_t sig = (size_t)b * 32 + c0 + c;
    float* gca4 = out + sig * L4;
    float* gcd4 = out + S * (size_t)L4 + sig * L4;
    float* gcd3 = out + 2 * S * (size_t)L4 + sig * L3;
    float* gcd2 = out + 2 * S * (size_t)L4 + S * (size_t)L3 + sig * L2;
    float* gcd1 = out + 2 * S * (size_t)L4 + S * (size_t)L3 + S * (size_t)L2 + sig * L1;

    // owned (exclusive, tile-partitioned) detail ranges; boundaries lie inside halo overlap
    const int o1lo = tile ? 264 * tile - 34 : 0;
    const int o1hi = (tile == 7) ? L1 : 264 * tile + 230;
    const int o2lo = tile ? 132 * tile - 10 : 0;
    const int o2hi = (tile == 7) ? L2 : 132 * tile + 122;
    const int o3lo = tile ? 66 * tile - 2 : 0;
    const int o3hi = (tile == 7) ? L3 : 66 * tile + 64;

    level_run<10, false>(bx, LPX, lox, b1, LP1, L1, lo1, hi1, gcd1, o1lo, o1hi, nullptr, c, slot);
    __syncthreads();
    level_run<5, false>(b1, LP1, lo1, b2, LP2, L2, lo2, hi2, gcd2, o2lo, o2hi, nullptr, c, slot);
    __syncthreads();
    level_run<3, false>(b2, LP2, lo2, b3, LP3, L3, lo3, hi3, gcd3, o3lo, o3hi, nullptr, c, slot);
    __syncthreads();
    level_run<2, true>(b3, LP3, lo3, nullptr, 0, L4, lo4, hi4, gcd4, lo4, hi4, gca4, c, slot);
}

extern "C" void kernel_launch(void* const* d_in, const int* in_sizes, int n_in,
                              void* d_out, int out_size, void* d_ws, size_t ws_size,
                              hipStream_t stream) {
    const float* x = (const float*)d_in[0];
    float* out = (float*)d_out;
    fused_dwt_kernel<<<dim3(2048), dim3(256), 0, stream>>>(x, out);
}

// Round 4
// 31.289 us; speedup vs baseline: 1.0936x; 1.0936x over previous
//
#include <hip/hip_runtime.h>

// Fully-fused 4-level db4 wavedec ('symmetric'), faithful to the JAX/pywt reference.
// x: [B=64, L=4096, C=32] f32.  Out flat concat: cA4,cD4,cD3,cD2,cD1 each [B,C,len].
// lens: 4096 -> 2051 -> 1029 -> 518 -> 262.
// Block = (batch, 4-channel group, tile of 33 cA4 outputs); 4096 blocks, 256 thr.
// Compute: register sliding window over transposed per-channel LDS rows
// (1 ds_read_b64 per output pair). All global writes staged in LDS and dumped
// coalesced (64 consecutive floats per wave), overlapped with next level.

#define NCH 4
// Row pitches (words): 6 + span + 7, pitch ≡ 2 (mod 4) for uniform bank maps.
#define LPX 634  // x span <= 618
#define LP1 322  // l1 span <= 306
#define LP2 166  // l2 span <= 150
#define LP3 86   // l3 span <= 72
#define CDPA 314 // cd staging for L1/L3 (span <= 306)
#define CDPB 154 // cd staging for L2/L4 (span <= 150)
#define CAP4 40  // cA4 staging (span <= 33)

template <int R, bool LAST>
__device__ __forceinline__ void level_run(
    const float* __restrict__ src, int PS, int srclo,
    float* __restrict__ dst, int PD, int DL,
    int lo, int hi,
    float* __restrict__ cdbuf, int CDP,
    float* __restrict__ cabuf,
    int c, int slot) {
    // db4 correlation kernels (dec_lo reversed = _H; dec_hi reversed).
    constexpr float FLO[8] = {
        0.23037781330885523f,  0.7148465705525415f,  0.6308807679295904f,
        -0.02798376941698385f, -0.18703481171888114f, 0.030841381835986965f,
        0.032883011666982945f, -0.010597401784997278f};
    constexpr float FHI[8] = {
        -0.010597401784997278f, -0.032883011666982945f, 0.030841381835986965f,
        0.18703481171888114f,  -0.02798376941698385f,  -0.6308807679295904f,
        0.7148465705525415f,   -0.23037781330885523f};

    const int span = hi - lo;
    int i0r = slot * R;
    if (i0r > span - R) i0r = span - R;  // clamp (duplicates are idempotent)
    const int i0 = lo + i0r;

    const float2* row2 = reinterpret_cast<const float2*>(src + c * PS);
    int p = i0 - (srclo >> 1);  // sample t at word t-srclo+6; first tap t=2i-6
    float2 f0 = row2[p], f1 = row2[p + 1], f2 = row2[p + 2];
    float* drow = LAST ? nullptr : dst + c * PD;
    float* cdrow = cdbuf + c * CDP - lo;
    float* carow = LAST ? cabuf + c * CAP4 - lo : nullptr;

#pragma unroll
    for (int r = 0; r < R; ++r) {
        const float2 f3 = row2[p + 3 + r];
        const int i = i0 + r;
        const float w0 = f0.x, w1 = f0.y, w2 = f1.x, w3 = f1.y;
        const float w4 = f2.x, w5 = f2.y, w6 = f3.x, w7 = f3.y;
        float a = FLO[0] * w0;
        a = fmaf(FLO[1], w1, a); a = fmaf(FLO[2], w2, a); a = fmaf(FLO[3], w3, a);
        a = fmaf(FLO[4], w4, a); a = fmaf(FLO[5], w5, a); a = fmaf(FLO[6], w6, a);
        a = fmaf(FLO[7], w7, a);
        float d = FHI[0] * w0;
        d = fmaf(FHI[1], w1, d); d = fmaf(FHI[2], w2, d); d = fmaf(FHI[3], w3, d);
        d = fmaf(FHI[4], w4, d); d = fmaf(FHI[5], w5, d); d = fmaf(FHI[6], w6, d);
        d = fmaf(FHI[7], w7, d);

        if constexpr (!LAST) {
            drow[i - lo + 6] = a;
            // reflection margins for next level (boundary tiles only)
            if (lo == 0 && i < 6) drow[5 - i] = a;
            if (hi == DL && i >= DL - 7) drow[(2 * DL - 1 - i) - lo + 6] = a;
        } else {
            carow[i] = a;
        }
        cdrow[i] = d;
        f0 = f1; f1 = f2; f2 = f3;
    }
}

__device__ __forceinline__ void dump_rows(
    const float* __restrict__ buf, int pitch, int bufLo,
    float* __restrict__ gbase, int rowLen, int ownLo, int ownHi, int tid) {
    const int span = ownHi - ownLo;
#pragma unroll
    for (int c2 = 0; c2 < NCH; ++c2) {
        float* g = gbase + (size_t)c2 * rowLen + ownLo;
        const float* s = buf + c2 * pitch + (ownLo - bufLo);
        for (int i = tid; i < span; i += 256) g[i] = s[i];
    }
}

__global__ __launch_bounds__(256) void fused_dwt_kernel(
    const float* __restrict__ x, float* __restrict__ out) {
    __shared__ __align__(16) float bx[NCH * LPX];
    __shared__ __align__(16) float b1[NCH * LP1];
    __shared__ __align__(16) float b2[NCH * LP2];
    __shared__ __align__(16) float b3[NCH * LP3];
    __shared__ __align__(16) float cdA[NCH * CDPA];
    __shared__ __align__(16) float cdB[NCH * CDPB];
    __shared__ __align__(16) float caB[NCH * CAP4];

    // XCD swizzle: 4096 blocks = 8 XCDs x 512 contiguous works, so the 8
    // channel-group siblings (consecutive works) share one XCD's L2.
    const int bid = blockIdx.x;
    const int work = (bid & 7) * 512 + (bid >> 3);
    const int cg = work & 7;           // channel group 0..7 (4 ch each)
    const int tile = (work >> 3) & 7;  // cA4 tile 0..7
    const int b = work >> 6;           // batch 0..63

    const int tid = threadIdx.x;
    const int c = tid & 3;
    const int slot = tid >> 2;  // 0..63
    const int c0 = cg * 4;

    const int L0 = 4096, L1 = 2051, L2 = 1029, L3 = 518, L4 = 262;

    const int lo4 = tile * 33, hi4 = min(L4, lo4 + 33);
    const int lo3 = max(0, 2 * lo4 - 6), hi3 = min(L3, 2 * hi4);
    const int lo2 = max(0, 2 * lo3 - 6), hi2 = min(L2, 2 * hi3);
    const int lo1 = max(0, 2 * lo2 - 6), hi1 = min(L1, 2 * hi2);
    const int lox = max(0, 2 * lo1 - 6), hix = min(L0, 2 * hi1);

    // ---- stage x tile into transposed rows (+ reflection margins) ----
    const float* xb = x + (size_t)b * L0 * 32 + c0;
    const int nx = hix - lox;
    for (int q = tid; q < nx; q += 256) {
        const int t = lox + q;
        const float4 v = *reinterpret_cast<const float4*>(xb + (size_t)t * 32);
        const float vv[4] = {v.x, v.y, v.z, v.w};
#pragma unroll
        for (int hh = 0; hh < 4; ++hh) {
            float* row = bx + hh * LPX;
            row[q + 6] = vv[hh];
            if (lox == 0 && t < 6) row[5 - t] = vv[hh];
            if (hix == L0 && t >= L0 - 7) row[(2 * L0 - 1 - t) - lox + 6] = vv[hh];
        }
    }
    __syncthreads();

    // d_out chunk bases for this block's 4 channels
    const size_t S = 2048;
    const size_t sigB = (size_t)b * 32 + c0;
    float* gca4 = out + sigB * L4;
    float* gcd4 = out + S * (size_t)L4 + sigB * L4;
    float* gcd3 = out + 2 * S * (size_t)L4 + sigB * L3;
    float* gcd2 = out + 2 * S * (size_t)L4 + S * (size_t)L3 + sigB * L2;
    float* gcd1 = out + 2 * S * (size_t)L4 + S * (size_t)L3 + S * (size_t)L2 + sigB * L1;

    // owned (exclusive, tile-partitioned) detail ranges
    const int o1lo = tile ? 264 * tile - 34 : 0;
    const int o1hi = (tile == 7) ? L1 : 264 * tile + 230;
    const int o2lo = tile ? 132 * tile - 10 : 0;
    const int o2hi = (tile == 7) ? L2 : 132 * tile + 122;
    const int o3lo = tile ? 66 * tile - 2 : 0;
    const int o3hi = (tile == 7) ? L3 : 66 * tile + 64;

    level_run<5, false>(bx, LPX, lox, b1, LP1, L1, lo1, hi1, cdA, CDPA, nullptr, c, slot);
    __syncthreads();

    dump_rows(cdA, CDPA, lo1, gcd1, L1, o1lo, o1hi, tid);
    level_run<3, false>(b1, LP1, lo1, b2, LP2, L2, lo2, hi2, cdB, CDPB, nullptr, c, slot);
    __syncthreads();

    dump_rows(cdB, CDPB, lo2, gcd2, L2, o2lo, o2hi, tid);
    level_run<2, false>(b2, LP2, lo2, b3, LP3, L3, lo3, hi3, cdA, CDPA, nullptr, c, slot);
    __syncthreads();

    dump_rows(cdA, CDPA, lo3, gcd3, L3, o3lo, o3hi, tid);
    level_run<1, true>(b3, LP3, lo3, nullptr, 0, L4, lo4, hi4, cdB, CDPB, caB, c, slot);
    __syncthreads();

    dump_rows(cdB, CDPB, lo4, gcd4, L4, lo4, hi4, tid);
    dump_rows(caB, CAP4, lo4, gca4, L4, lo4, hi4, tid);
}

extern "C" void kernel_launch(void* const* d_in, const int* in_sizes, int n_in,
                              void* d_out, int out_size, void* d_ws, size_t ws_size,
                              hipStream_t stream) {
    const float* x = (const float*)d_in[0];
    float* out = (float*)d_out;
    fused_dwt_kernel<<<dim3(4096), dim3(256), 0, stream>>>(x, out);
}